// Round 7
// baseline (2277.665 us; speedup 1.0000x reference)
//
#include <hip/hip_runtime.h>

#define N_TOKENS 131072
#define DIM 64
#define N_EMBED 1024
#define DECAYF 0.99f
#define OMDF 0.01f
#define EPSF 1e-5f
#define SUM_TPB 128   // tokens per block in vq_sum (4 waves x 32)

#define TOK_TILE 128
#define CODE_CHUNK 128
#define NCHUNK (N_EMBED / CODE_CHUNK)
#define APAD 68       // 64 + 4 floats: bank shift 4/row, keeps 16B alignment
#define BPAD 36       // 32 + 4 floats (k-half rows)

// Output layout (floats), reference return order:
// quantize_st [131072*64], diff [1], embed_ind [131072], new_embed [64*1024],
// new_cluster_size [1024], new_embed_avg [64*1024]
#define OFF_QST  ((size_t)0)
#define OFF_DIFF ((size_t)8388608)
#define OFF_IND  ((size_t)8388609)
#define OFF_NE   ((size_t)8519681)
#define OFF_NCS  ((size_t)8585217)
#define OFF_NEA  ((size_t)8586241)

// ws layout: floats then ints
// f[0] diff_sum, f[1] n_val, f[1026..66562) es, f[66562..132098) embedT,
// f[132098..133122) cnorm; ints at f-index 133632:
// cnt_i[1024], start_i[1024], cursor_i[1024], sorted[131072], scode[131072]
#define WS_DIFF   0
#define WS_NVAL   1
#define WS_ES     1026
#define WS_ET     66562
#define WS_CNORM  132098
#define WS_IWS    133632

__global__ __launch_bounds__(256) void vq_prep_transpose(
    const float* __restrict__ embed, float* __restrict__ embedT)
{
    int i = blockIdx.x * 256 + threadIdx.x;        // 65536 elems, coalesced read
    int d = i >> 10, e = i & 1023;
    embedT[e * DIM + d] = embed[i];
}

__global__ __launch_bounds__(256) void vq_prep_norm(
    const float* __restrict__ embedT, float* __restrict__ cnorm)
{
    int e = blockIdx.x * 256 + threadIdx.x;        // 1024
    const float4* c = (const float4*)(embedT + (size_t)e * DIM);
    float s = 0.f;
#pragma unroll
    for (int i = 0; i < 16; ++i) {
        float4 v = c[i];
        s = fmaf(v.x, v.x, s); s = fmaf(v.y, v.y, s);
        s = fmaf(v.z, v.z, s); s = fmaf(v.w, v.w, s);
    }
    cnorm[e] = s;
}

// Register-tiled distance GEMM + fused argmin.
// Block tile: 128 tokens x 128 codes. 4 waves as 2x2; wave tile 64x64;
// lane grid 8x8; per-thread 8x8 accumulators.
// Micro-kernel order (spill-proof): per k4 step preload a4[8] (32 regs),
// then one b4 at a time -> peak live ~115 VGPR (round 6's b4[8] variant
// spilled: 4.9GB FETCH / 3.0GB WRITE of scratch traffic).
__global__ __launch_bounds__(256, 2) void vq_main(
    const float* __restrict__ x, const float* __restrict__ embedT,
    const float* __restrict__ cnorm, float* __restrict__ out,
    float* __restrict__ diff_sum, int* __restrict__ cnt_i)
{
    __shared__ float xs[TOK_TILE * APAD];       // 34816 B: x tile, padded rows
    __shared__ float ecs[CODE_CHUNK * BPAD];    // 18432 B: code chunk, one k-half
    __shared__ float cnc[CODE_CHUNK];
    __shared__ int   lhist[N_EMBED];            // 4 KB histogram
    __shared__ float red_d[2 * TOK_TILE];
    __shared__ int   red_i[2 * TOK_TILE];
    __shared__ int   bi_l[TOK_TILE];

    const int t = threadIdx.x;
    const int w = t >> 6, lane = t & 63;
    const int wr = w >> 1, wc = w & 1;
    const int r = lane >> 3, c = lane & 7;

    for (int i = t; i < N_EMBED; i += 256) lhist[i] = 0;

    // stage A: 128 x rows -> padded LDS rows (2048 float4 / 256 thr = 8 each)
    {
        const float4* xsrc = (const float4*)(x + (size_t)blockIdx.x * TOK_TILE * DIM);
#pragma unroll
        for (int j = 0; j < 8; ++j) {
            int g = j * 256 + t;
            int tok = g >> 4, kk = (g & 15) << 2;
            float4 v = xsrc[g];
            *(float4*)(xs + tok * APAD + kk) = v;
        }
    }

    float best[8];
    int   bidx[8];
#pragma unroll
    for (int i = 0; i < 8; ++i) { best[i] = 3.4e38f; bidx[i] = 0; }

    for (int chunk = 0; chunk < NCHUNK; ++chunk) {
        float acc[8][8];
#pragma unroll
        for (int i = 0; i < 8; ++i)
#pragma unroll
            for (int j = 0; j < 8; ++j) acc[i][j] = 0.f;

#pragma unroll
        for (int kh = 0; kh < 2; ++kh) {
            __syncthreads();   // prev compute / cnc consumers done
            {   // stage B k-half: 128 codes x 32 k (1024 float4 / 256 thr = 4)
#pragma unroll
                for (int j = 0; j < 4; ++j) {
                    int g = j * 256 + t;
                    int code = g >> 3, kk = (g & 7) << 2;
                    float4 v = *(const float4*)(embedT +
                        ((size_t)(chunk * CODE_CHUNK + code)) * DIM + kh * 32 + kk);
                    *(float4*)(ecs + code * BPAD + kk) = v;
                }
                if (kh == 0 && t < CODE_CHUNK) cnc[t] = cnorm[chunk * CODE_CHUNK + t];
            }
            __syncthreads();

            const float* xbase = xs + (wr * 64) * APAD + kh * 32;
            const float* bbase = ecs + (wc * 64) * BPAD;
#pragma unroll
            for (int ks = 0; ks < 8; ++ks) {
                float4 a4[8];
#pragma unroll
                for (int i = 0; i < 8; ++i)
                    a4[i] = *(const float4*)(xbase + (r + 8 * i) * APAD + ks * 4);
#pragma unroll
                for (int j = 0; j < 8; ++j) {
                    float4 b4 = *(const float4*)(bbase + (c + 8 * j) * BPAD + ks * 4);
#pragma unroll
                    for (int i = 0; i < 8; ++i) {
                        acc[i][j] = fmaf(a4[i].x, b4.x, acc[i][j]);
                        acc[i][j] = fmaf(a4[i].y, b4.y, acc[i][j]);
                        acc[i][j] = fmaf(a4[i].z, b4.z, acc[i][j]);
                        acc[i][j] = fmaf(a4[i].w, b4.w, acc[i][j]);
                    }
                }
            }
        }

        // dists + running argmin (codes ascending: strict < = first-index ties)
#pragma unroll
        for (int j = 0; j < 8; ++j) {
            int lc = wc * 64 + c + 8 * j;
            float cn = cnc[lc];
            int gcode = chunk * CODE_CHUNK + lc;
#pragma unroll
            for (int i = 0; i < 8; ++i) {
                float dist = fmaf(-2.f, acc[i][j], cn);
                if (dist < best[i]) { best[i] = dist; bidx[i] = gcode; }
            }
        }
    }

    // reduce over lane columns (c bits = lane bits 0..2)
#pragma unroll
    for (int i = 0; i < 8; ++i) {
        float d = best[i]; int bi = bidx[i];
#pragma unroll
        for (int m = 1; m < 8; m <<= 1) {
            float d2 = __shfl_xor(d, m, 64);
            int   i2 = __shfl_xor(bi, m, 64);
            if (d2 < d || (d2 == d && i2 < bi)) { d = d2; bi = i2; }
        }
        if (c == 0) {
            int tok = wr * 64 + r + 8 * i;
            red_d[wc * TOK_TILE + tok] = d;
            red_i[wc * TOK_TILE + tok] = bi;
        }
    }
    __syncthreads();

    if (t < TOK_TILE) {
        float d0 = red_d[t];            int i0 = red_i[t];
        float d1 = red_d[TOK_TILE + t]; int i1 = red_i[TOK_TILE + t];
        int bi = (d1 < d0 || (d1 == d0 && i1 < i0)) ? i1 : i0;
        bi_l[t] = bi;
        out[OFF_IND + (size_t)blockIdx.x * TOK_TILE + t] = (float)bi;
        atomicAdd(&lhist[bi], 1);
    }
    __syncthreads();

    // quantize write (coalesced) + diff partials
    float ds = 0.f;
    {
        const float4* et4 = (const float4*)embedT;
        float4* qst = (float4*)(out + OFF_QST + (size_t)blockIdx.x * TOK_TILE * DIM);
#pragma unroll
        for (int j = 0; j < 8; ++j) {
            int g = j * 256 + t;
            int tok = g >> 4, f = g & 15;
            int bi = bi_l[tok];
            float4 q = et4[bi * 16 + f];
            float4 xv = *(const float4*)(xs + tok * APAD + (f << 2));
            qst[g] = q;                                // x + stopgrad(q-x) == q
            float ex = q.x - xv.x, ey = q.y - xv.y, ez = q.z - xv.z, ew = q.w - xv.w;
            ds = fmaf(ex, ex, ds); ds = fmaf(ey, ey, ds);
            ds = fmaf(ez, ez, ds); ds = fmaf(ew, ew, ds);
        }
    }
#pragma unroll
    for (int o = 32; o > 0; o >>= 1) ds += __shfl_down(ds, o, 64);
    if (lane == 0) atomicAdd(diff_sum, ds);

    // flush histogram
    for (int i = t; i < N_EMBED; i += 256) {
        int cv = lhist[i];
        if (cv) atomicAdd(&cnt_i[i], cv);
    }
}

// single block, 1024 threads: exclusive prefix over cnt_i -> cursor_i
__global__ __launch_bounds__(1024) void vq_start(
    const int* __restrict__ cnt_i, int* __restrict__ cursor_i)
{
    __shared__ int sc[N_EMBED];
    int e = threadIdx.x;
    int c = cnt_i[e];
    sc[e] = c;
    __syncthreads();
#pragma unroll
    for (int off = 1; off < N_EMBED; off <<= 1) {
        int v = (e >= off) ? sc[e - off] : 0;
        __syncthreads();
        sc[e] += v;
        __syncthreads();
    }
    cursor_i[e] = sc[e] - c;
}

// 512 blocks x 256: bin token ids (and their code) into sorted[]/scode[].
__global__ __launch_bounds__(256) void vq_sort(
    const float* __restrict__ out, int* __restrict__ cursor_i,
    int* __restrict__ sorted, int* __restrict__ scode)
{
    __shared__ int lh[N_EMBED];
    __shared__ int lbase[N_EMBED];
    int t = threadIdx.x;
    for (int i = t; i < N_EMBED; i += 256) lh[i] = 0;
    __syncthreads();
    int tok = blockIdx.x * 256 + t;
    int e = (int)out[OFF_IND + tok];                  // exact small ints in float
    int p = atomicAdd(&lh[e], 1);                     // within-block rank (LDS)
    __syncthreads();
    for (int i = t; i < N_EMBED; i += 256) {
        int c = lh[i];
        if (c) lbase[i] = atomicAdd(&cursor_i[i], c); // reserve [base, base+c)
    }
    __syncthreads();
    int pos = lbase[e] + p;
    sorted[pos] = tok;
    scode[pos] = e;
}

// Token-balanced segment sum: 1024 blocks x 128 tokens. Wave lane = dim.
__global__ __launch_bounds__(256) void vq_sum(
    const float* __restrict__ x, const int* __restrict__ sorted,
    const int* __restrict__ scode, float* __restrict__ es)
{
    __shared__ int ltok[SUM_TPB];
    __shared__ int lcode[SUM_TPB];
    const int t = threadIdx.x;
    const int base = blockIdx.x * SUM_TPB;
    if (t < SUM_TPB) {
        ltok[t]  = sorted[base + t];
        lcode[t] = scode[base + t];
    }
    __syncthreads();

    const int w = t >> 6, d = t & 63;
    const int i0 = w * (SUM_TPB / 4);                 // 32 tokens per wave
    int   cur = lcode[i0];
    float acc = 0.f;
#pragma unroll 4
    for (int i = i0; i < i0 + SUM_TPB / 4; ++i) {
        int e = lcode[i];                             // wave-uniform
        if (e != cur) {                               // uniform branch
            atomicAdd(&es[(size_t)cur * DIM + d], acc);
            acc = 0.f;
            cur = e;
        }
        acc += x[(size_t)ltok[i] * DIM + d];          // 256B coalesced row read
    }
    atomicAdd(&es[(size_t)cur * DIM + d], acc);
}

__global__ __launch_bounds__(1024) void vq_final1(
    const float* __restrict__ cluster_size, const int* __restrict__ cnt_i,
    const float* __restrict__ diff_sum, float* __restrict__ out,
    float* __restrict__ n_val)
{
    int e = threadIdx.x;                            // single block of 1024
    float ncs = cluster_size[e] * DECAYF + OMDF * (float)cnt_i[e];
    out[OFF_NCS + e] = ncs;
    __shared__ float red[16];
    float s = ncs;
#pragma unroll
    for (int o = 32; o > 0; o >>= 1) s += __shfl_down(s, o, 64);
    if ((e & 63) == 0) red[e >> 6] = s;
    __syncthreads();
    if (e == 0) {
        float nsum = 0.f;
#pragma unroll
        for (int i = 0; i < 16; ++i) nsum += red[i];
        *n_val = nsum;
        out[OFF_DIFF] = *diff_sum / (float)((size_t)N_TOKENS * DIM);
    }
}

__global__ __launch_bounds__(256) void vq_final2(
    const float* __restrict__ embed_avg, const float* __restrict__ es,
    const float* __restrict__ n_val, float* __restrict__ out)
{
    int i = blockIdx.x * 256 + threadIdx.x;         // 65536, [d][e] flat
    int e = i & 1023, d = i >> 10;
    float nea = embed_avg[i] * DECAYF + OMDF * es[(size_t)e * DIM + d];
    out[OFF_NEA + i] = nea;
    float ncs = out[OFF_NCS + e];
    float nsum = *n_val;
    float cs = (ncs + EPSF) / (nsum + (float)N_EMBED * EPSF) * nsum;
    out[OFF_NE + i] = nea / cs;
}

extern "C" void kernel_launch(void* const* d_in, const int* in_sizes, int n_in,
                              void* d_out, int out_size, void* d_ws, size_t ws_size,
                              hipStream_t stream)
{
    const float* x            = (const float*)d_in[0];
    const float* embed        = (const float*)d_in[1];
    const float* cluster_size = (const float*)d_in[2];
    const float* embed_avg    = (const float*)d_in[3];
    float* out = (float*)d_out;
    float* ws  = (float*)d_ws;

    float* diff_sum = ws + WS_DIFF;
    float* n_val    = ws + WS_NVAL;
    float* es       = ws + WS_ES;
    float* embedT   = ws + WS_ET;
    float* cnorm    = ws + WS_CNORM;
    int*   iws      = (int*)(ws + WS_IWS);
    int*   cnt_i    = iws;
    int*   cursor_i = iws + 2 * N_EMBED;
    int*   sorted   = iws + 3 * N_EMBED;
    int*   scode    = sorted + N_TOKENS;

    hipMemsetAsync(diff_sum, 0, 2 * sizeof(float), stream);
    hipMemsetAsync(es, 0, N_EMBED * DIM * sizeof(float), stream);   // atomic accumulator
    hipMemsetAsync(cnt_i, 0, N_EMBED * sizeof(int), stream);

    vq_prep_transpose<<<256, 256, 0, stream>>>(embed, embedT);
    vq_prep_norm<<<4, 256, 0, stream>>>(embedT, cnorm);
    vq_main<<<N_TOKENS / TOK_TILE, 256, 0, stream>>>(x, embedT, cnorm, out, diff_sum, cnt_i);
    vq_start<<<1, 1024, 0, stream>>>(cnt_i, cursor_i);
    vq_sort<<<N_TOKENS / 256, 256, 0, stream>>>(out, cursor_i, sorted, scode);
    vq_sum<<<N_TOKENS / SUM_TPB, 256, 0, stream>>>(x, sorted, scode, es);
    vq_final1<<<1, 1024, 0, stream>>>(cluster_size, cnt_i, diff_sum, out, n_val);
    vq_final2<<<256, 256, 0, stream>>>(embed_avg, es, n_val, out);
}

// Round 8
// 735.898 us; speedup vs baseline: 3.0951x; 3.0951x over previous
//
#include <hip/hip_runtime.h>

#define N_TOKENS 131072
#define DIM 64
#define N_EMBED 1024
#define DECAYF 0.99f
#define OMDF 0.01f
#define EPSF 1e-5f
#define SUM_TPB 128   // tokens per block in vq_sum (4 waves x 32)

#define TOK_TILE 128
#define CODE_CHUNK 128
#define NCHUNK (N_EMBED / CODE_CHUNK)
#define APAD 68       // 64 + 4 floats: bank shift 4/row, keeps 16B alignment
#define BPAD 36       // 32 + 4 floats (k-half rows)

// Output layout (floats), reference return order:
// quantize_st [131072*64], diff [1], embed_ind [131072], new_embed [64*1024],
// new_cluster_size [1024], new_embed_avg [64*1024]
#define OFF_QST  ((size_t)0)
#define OFF_DIFF ((size_t)8388608)
#define OFF_IND  ((size_t)8388609)
#define OFF_NE   ((size_t)8519681)
#define OFF_NCS  ((size_t)8585217)
#define OFF_NEA  ((size_t)8586241)

// ws layout: floats then ints
// f[0] diff_sum, f[1] n_val, f[1026..66562) es, f[66562..132098) embedT,
// f[132098..133122) cnorm; ints at f-index 133632:
// cnt_i[1024], start_i[1024], cursor_i[1024], sorted[131072], scode[131072]
#define WS_DIFF   0
#define WS_NVAL   1
#define WS_ES     1026
#define WS_ET     66562
#define WS_CNORM  132098
#define WS_IWS    133632

__global__ __launch_bounds__(256) void vq_prep_transpose(
    const float* __restrict__ embed, float* __restrict__ embedT)
{
    int i = blockIdx.x * 256 + threadIdx.x;        // 65536 elems, coalesced read
    int d = i >> 10, e = i & 1023;
    embedT[e * DIM + d] = embed[i];
}

__global__ __launch_bounds__(256) void vq_prep_norm(
    const float* __restrict__ embedT, float* __restrict__ cnorm)
{
    int e = blockIdx.x * 256 + threadIdx.x;        // 1024
    const float4* c = (const float4*)(embedT + (size_t)e * DIM);
    float s = 0.f;
#pragma unroll
    for (int i = 0; i < 16; ++i) {
        float4 v = c[i];
        s = fmaf(v.x, v.x, s); s = fmaf(v.y, v.y, s);
        s = fmaf(v.z, v.z, s); s = fmaf(v.w, v.w, s);
    }
    cnorm[e] = s;
}

// Register-tiled distance GEMM + fused argmin.
// Block tile: 128 tokens x 128 codes. 4 waves as 2x2; wave tile 64x64;
// lane grid 8x8; per-thread 8x8 accumulators.
// __launch_bounds__(256, 1): rounds 6/7 proved that any tighter occupancy
// request caps VGPR at 128 and spills the acc tile -> 8 GB scratch traffic.
// LDS (59 KB) limits to 2 blocks/CU regardless, so the cap bought nothing.
__global__ __launch_bounds__(256, 1) void vq_main(
    const float* __restrict__ x, const float* __restrict__ embedT,
    const float* __restrict__ cnorm, float* __restrict__ out,
    float* __restrict__ diff_sum, int* __restrict__ cnt_i)
{
    __shared__ float xs[TOK_TILE * APAD];       // 34816 B: x tile, padded rows
    __shared__ float ecs[CODE_CHUNK * BPAD];    // 18432 B: code chunk, one k-half
    __shared__ float cnc[CODE_CHUNK];
    __shared__ int   lhist[N_EMBED];            // 4 KB histogram
    __shared__ float red_d[2 * TOK_TILE];
    __shared__ int   red_i[2 * TOK_TILE];
    __shared__ int   bi_l[TOK_TILE];

    const int t = threadIdx.x;
    const int w = t >> 6, lane = t & 63;
    const int wr = w >> 1, wc = w & 1;
    const int r = lane >> 3, c = lane & 7;

    for (int i = t; i < N_EMBED; i += 256) lhist[i] = 0;

    // stage A: 128 x rows -> padded LDS rows (2048 float4 / 256 thr = 8 each)
    {
        const float4* xsrc = (const float4*)(x + (size_t)blockIdx.x * TOK_TILE * DIM);
#pragma unroll
        for (int j = 0; j < 8; ++j) {
            int g = j * 256 + t;
            int tok = g >> 4, kk = (g & 15) << 2;
            float4 v = xsrc[g];
            *(float4*)(xs + tok * APAD + kk) = v;
        }
    }

    float best[8];
    int   bidx[8];
#pragma unroll
    for (int i = 0; i < 8; ++i) { best[i] = 3.4e38f; bidx[i] = 0; }

    for (int chunk = 0; chunk < NCHUNK; ++chunk) {
        float acc[8][8];
#pragma unroll
        for (int i = 0; i < 8; ++i)
#pragma unroll
            for (int j = 0; j < 8; ++j) acc[i][j] = 0.f;

#pragma unroll
        for (int kh = 0; kh < 2; ++kh) {
            __syncthreads();   // prev compute / cnc consumers done
            {   // stage B k-half: 128 codes x 32 k (1024 float4 / 256 thr = 4)
#pragma unroll
                for (int j = 0; j < 4; ++j) {
                    int g = j * 256 + t;
                    int code = g >> 3, kk = (g & 7) << 2;
                    float4 v = *(const float4*)(embedT +
                        ((size_t)(chunk * CODE_CHUNK + code)) * DIM + kh * 32 + kk);
                    *(float4*)(ecs + code * BPAD + kk) = v;
                }
                if (kh == 0 && t < CODE_CHUNK) cnc[t] = cnorm[chunk * CODE_CHUNK + t];
            }
            __syncthreads();

            const float* xbase = xs + (wr * 64) * APAD + kh * 32;
            const float* bbase = ecs + (wc * 64) * BPAD;
#pragma unroll
            for (int ks = 0; ks < 8; ++ks) {
                float4 a4[8];
#pragma unroll
                for (int i = 0; i < 8; ++i)
                    a4[i] = *(const float4*)(xbase + (r + 8 * i) * APAD + ks * 4);
#pragma unroll
                for (int j = 0; j < 8; ++j) {
                    float4 b4 = *(const float4*)(bbase + (c + 8 * j) * BPAD + ks * 4);
#pragma unroll
                    for (int i = 0; i < 8; ++i) {
                        acc[i][j] = fmaf(a4[i].x, b4.x, acc[i][j]);
                        acc[i][j] = fmaf(a4[i].y, b4.y, acc[i][j]);
                        acc[i][j] = fmaf(a4[i].z, b4.z, acc[i][j]);
                        acc[i][j] = fmaf(a4[i].w, b4.w, acc[i][j]);
                    }
                }
            }
        }

        // dists + running argmin (codes ascending: strict < = first-index ties)
#pragma unroll
        for (int j = 0; j < 8; ++j) {
            int lc = wc * 64 + c + 8 * j;
            float cn = cnc[lc];
            int gcode = chunk * CODE_CHUNK + lc;
#pragma unroll
            for (int i = 0; i < 8; ++i) {
                float dist = fmaf(-2.f, acc[i][j], cn);
                if (dist < best[i]) { best[i] = dist; bidx[i] = gcode; }
            }
        }
    }

    // reduce over lane columns (c bits = lane bits 0..2)
#pragma unroll
    for (int i = 0; i < 8; ++i) {
        float d = best[i]; int bi = bidx[i];
#pragma unroll
        for (int m = 1; m < 8; m <<= 1) {
            float d2 = __shfl_xor(d, m, 64);
            int   i2 = __shfl_xor(bi, m, 64);
            if (d2 < d || (d2 == d && i2 < bi)) { d = d2; bi = i2; }
        }
        if (c == 0) {
            int tok = wr * 64 + r + 8 * i;
            red_d[wc * TOK_TILE + tok] = d;
            red_i[wc * TOK_TILE + tok] = bi;
        }
    }
    __syncthreads();

    if (t < TOK_TILE) {
        float d0 = red_d[t];            int i0 = red_i[t];
        float d1 = red_d[TOK_TILE + t]; int i1 = red_i[TOK_TILE + t];
        int bi = (d1 < d0 || (d1 == d0 && i1 < i0)) ? i1 : i0;
        bi_l[t] = bi;
        out[OFF_IND + (size_t)blockIdx.x * TOK_TILE + t] = (float)bi;
        atomicAdd(&lhist[bi], 1);
    }
    __syncthreads();

    // quantize write (coalesced) + diff partials
    float ds = 0.f;
    {
        const float4* et4 = (const float4*)embedT;
        float4* qst = (float4*)(out + OFF_QST + (size_t)blockIdx.x * TOK_TILE * DIM);
#pragma unroll
        for (int j = 0; j < 8; ++j) {
            int g = j * 256 + t;
            int tok = g >> 4, f = g & 15;
            int bi = bi_l[tok];
            float4 q = et4[bi * 16 + f];
            float4 xv = *(const float4*)(xs + tok * APAD + (f << 2));
            qst[g] = q;                                // x + stopgrad(q-x) == q
            float ex = q.x - xv.x, ey = q.y - xv.y, ez = q.z - xv.z, ew = q.w - xv.w;
            ds = fmaf(ex, ex, ds); ds = fmaf(ey, ey, ds);
            ds = fmaf(ez, ez, ds); ds = fmaf(ew, ew, ds);
        }
    }
#pragma unroll
    for (int o = 32; o > 0; o >>= 1) ds += __shfl_down(ds, o, 64);
    if (lane == 0) atomicAdd(diff_sum, ds);

    // flush histogram
    for (int i = t; i < N_EMBED; i += 256) {
        int cv = lhist[i];
        if (cv) atomicAdd(&cnt_i[i], cv);
    }
}

// single block, 1024 threads: exclusive prefix over cnt_i -> cursor_i
__global__ __launch_bounds__(1024) void vq_start(
    const int* __restrict__ cnt_i, int* __restrict__ cursor_i)
{
    __shared__ int sc[N_EMBED];
    int e = threadIdx.x;
    int c = cnt_i[e];
    sc[e] = c;
    __syncthreads();
#pragma unroll
    for (int off = 1; off < N_EMBED; off <<= 1) {
        int v = (e >= off) ? sc[e - off] : 0;
        __syncthreads();
        sc[e] += v;
        __syncthreads();
    }
    cursor_i[e] = sc[e] - c;
}

// 512 blocks x 256: bin token ids (and their code) into sorted[]/scode[].
__global__ __launch_bounds__(256) void vq_sort(
    const float* __restrict__ out, int* __restrict__ cursor_i,
    int* __restrict__ sorted, int* __restrict__ scode)
{
    __shared__ int lh[N_EMBED];
    __shared__ int lbase[N_EMBED];
    int t = threadIdx.x;
    for (int i = t; i < N_EMBED; i += 256) lh[i] = 0;
    __syncthreads();
    int tok = blockIdx.x * 256 + t;
    int e = (int)out[OFF_IND + tok];                  // exact small ints in float
    int p = atomicAdd(&lh[e], 1);                     // within-block rank (LDS)
    __syncthreads();
    for (int i = t; i < N_EMBED; i += 256) {
        int c = lh[i];
        if (c) lbase[i] = atomicAdd(&cursor_i[i], c); // reserve [base, base+c)
    }
    __syncthreads();
    int pos = lbase[e] + p;
    sorted[pos] = tok;
    scode[pos] = e;
}

// Token-balanced segment sum: 1024 blocks x 128 tokens. Wave lane = dim.
__global__ __launch_bounds__(256) void vq_sum(
    const float* __restrict__ x, const int* __restrict__ sorted,
    const int* __restrict__ scode, float* __restrict__ es)
{
    __shared__ int ltok[SUM_TPB];
    __shared__ int lcode[SUM_TPB];
    const int t = threadIdx.x;
    const int base = blockIdx.x * SUM_TPB;
    if (t < SUM_TPB) {
        ltok[t]  = sorted[base + t];
        lcode[t] = scode[base + t];
    }
    __syncthreads();

    const int w = t >> 6, d = t & 63;
    const int i0 = w * (SUM_TPB / 4);                 // 32 tokens per wave
    int   cur = lcode[i0];
    float acc = 0.f;
#pragma unroll 4
    for (int i = i0; i < i0 + SUM_TPB / 4; ++i) {
        int e = lcode[i];                             // wave-uniform
        if (e != cur) {                               // uniform branch
            atomicAdd(&es[(size_t)cur * DIM + d], acc);
            acc = 0.f;
            cur = e;
        }
        acc += x[(size_t)ltok[i] * DIM + d];          // 256B coalesced row read
    }
    atomicAdd(&es[(size_t)cur * DIM + d], acc);
}

__global__ __launch_bounds__(1024) void vq_final1(
    const float* __restrict__ cluster_size, const int* __restrict__ cnt_i,
    const float* __restrict__ diff_sum, float* __restrict__ out,
    float* __restrict__ n_val)
{
    int e = threadIdx.x;                            // single block of 1024
    float ncs = cluster_size[e] * DECAYF + OMDF * (float)cnt_i[e];
    out[OFF_NCS + e] = ncs;
    __shared__ float red[16];
    float s = ncs;
#pragma unroll
    for (int o = 32; o > 0; o >>= 1) s += __shfl_down(s, o, 64);
    if ((e & 63) == 0) red[e >> 6] = s;
    __syncthreads();
    if (e == 0) {
        float nsum = 0.f;
#pragma unroll
        for (int i = 0; i < 16; ++i) nsum += red[i];
        *n_val = nsum;
        out[OFF_DIFF] = *diff_sum / (float)((size_t)N_TOKENS * DIM);
    }
}

__global__ __launch_bounds__(256) void vq_final2(
    const float* __restrict__ embed_avg, const float* __restrict__ es,
    const float* __restrict__ n_val, float* __restrict__ out)
{
    int i = blockIdx.x * 256 + threadIdx.x;         // 65536, [d][e] flat
    int e = i & 1023, d = i >> 10;
    float nea = embed_avg[i] * DECAYF + OMDF * es[(size_t)e * DIM + d];
    out[OFF_NEA + i] = nea;
    float ncs = out[OFF_NCS + e];
    float nsum = *n_val;
    float cs = (ncs + EPSF) / (nsum + (float)N_EMBED * EPSF) * nsum;
    out[OFF_NE + i] = nea / cs;
}

extern "C" void kernel_launch(void* const* d_in, const int* in_sizes, int n_in,
                              void* d_out, int out_size, void* d_ws, size_t ws_size,
                              hipStream_t stream)
{
    const float* x            = (const float*)d_in[0];
    const float* embed        = (const float*)d_in[1];
    const float* cluster_size = (const float*)d_in[2];
    const float* embed_avg    = (const float*)d_in[3];
    float* out = (float*)d_out;
    float* ws  = (float*)d_ws;

    float* diff_sum = ws + WS_DIFF;
    float* n_val    = ws + WS_NVAL;
    float* es       = ws + WS_ES;
    float* embedT   = ws + WS_ET;
    float* cnorm    = ws + WS_CNORM;
    int*   iws      = (int*)(ws + WS_IWS);
    int*   cnt_i    = iws;
    int*   cursor_i = iws + 2 * N_EMBED;
    int*   sorted   = iws + 3 * N_EMBED;
    int*   scode    = sorted + N_TOKENS;

    hipMemsetAsync(diff_sum, 0, 2 * sizeof(float), stream);
    hipMemsetAsync(es, 0, N_EMBED * DIM * sizeof(float), stream);   // atomic accumulator
    hipMemsetAsync(cnt_i, 0, N_EMBED * sizeof(int), stream);

    vq_prep_transpose<<<256, 256, 0, stream>>>(embed, embedT);
    vq_prep_norm<<<4, 256, 0, stream>>>(embedT, cnorm);
    vq_main<<<N_TOKENS / TOK_TILE, 256, 0, stream>>>(x, embedT, cnorm, out, diff_sum, cnt_i);
    vq_start<<<1, 1024, 0, stream>>>(cnt_i, cursor_i);
    vq_sort<<<N_TOKENS / 256, 256, 0, stream>>>(out, cursor_i, sorted, scode);
    vq_sum<<<N_TOKENS / SUM_TPB, 256, 0, stream>>>(x, sorted, scode, es);
    vq_final1<<<1, 1024, 0, stream>>>(cluster_size, cnt_i, diff_sum, out, n_val);
    vq_final2<<<256, 256, 0, stream>>>(embed_avg, es, n_val, out);
}

// Round 9
// 355.857 us; speedup vs baseline: 6.4005x; 2.0680x over previous
//
#include <hip/hip_runtime.h>

#define N_TOKENS 131072
#define DIM 64
#define N_EMBED 1024
#define DECAYF 0.99f
#define OMDF 0.01f
#define EPSF 1e-5f
#define SUM_TPB 128   // tokens per block in vq_sum (4 waves x 32)

#define TOK_TILE 128
#define CODE_CHUNK 128
#define NCHUNK (N_EMBED / CODE_CHUNK)
#define APAD 68       // 64 + 4 floats: bank shift 4/row, keeps 16B alignment
#define BPAD 36       // 32 + 4 floats (k-half rows)

// Output layout (floats), reference return order:
// quantize_st [131072*64], diff [1], embed_ind [131072], new_embed [64*1024],
// new_cluster_size [1024], new_embed_avg [64*1024]
#define OFF_QST  ((size_t)0)
#define OFF_DIFF ((size_t)8388608)
#define OFF_IND  ((size_t)8388609)
#define OFF_NE   ((size_t)8519681)
#define OFF_NCS  ((size_t)8585217)
#define OFF_NEA  ((size_t)8586241)

// ws layout: floats then ints
// f[0] diff_sum, f[1] n_val, f[1026..66562) es, f[66562..132098) embedT,
// f[132098..133122) cnorm; ints at f-index 133632:
// cnt_i[1024], start_i[1024], cursor_i[1024], sorted[131072], scode[131072]
#define WS_DIFF   0
#define WS_NVAL   1
#define WS_ES     1026
#define WS_ET     66562
#define WS_CNORM  132098
#define WS_IWS    133632

__global__ __launch_bounds__(256) void vq_prep_transpose(
    const float* __restrict__ embed, float* __restrict__ embedT)
{
    int i = blockIdx.x * 256 + threadIdx.x;        // 65536 elems, coalesced read
    int d = i >> 10, e = i & 1023;
    embedT[e * DIM + d] = embed[i];
}

__global__ __launch_bounds__(256) void vq_prep_norm(
    const float* __restrict__ embedT, float* __restrict__ cnorm)
{
    int e = blockIdx.x * 256 + threadIdx.x;        // 1024
    const float4* c = (const float4*)(embedT + (size_t)e * DIM);
    float s = 0.f;
#pragma unroll
    for (int i = 0; i < 16; ++i) {
        float4 v = c[i];
        s = fmaf(v.x, v.x, s); s = fmaf(v.y, v.y, s);
        s = fmaf(v.z, v.z, s); s = fmaf(v.w, v.w, s);
    }
    cnorm[e] = s;
}

// Register-tiled distance GEMM + fused argmin.
// Block tile: 128 tokens x 128 codes. 4 waves as 2x2; wave tile 64x64;
// lane grid 8x8; per-thread 8x8 accumulators.
// ks loop is unroll-1: full unroll let the scheduler hoist all 64 a4/b4
// loads of a k-half, blowing past 256 VGPRs (r8: 832 MB scratch WRITE).
// Bounding the window keeps live ~200 regs: acc 64 + a4 32 + b4 32 + misc.
__global__ __launch_bounds__(256, 1) void vq_main(
    const float* __restrict__ x, const float* __restrict__ embedT,
    const float* __restrict__ cnorm, float* __restrict__ out,
    float* __restrict__ diff_sum, int* __restrict__ cnt_i)
{
    __shared__ float xs[TOK_TILE * APAD];       // 34816 B: x tile, padded rows
    __shared__ float ecs[CODE_CHUNK * BPAD];    // 18432 B: code chunk, one k-half
    __shared__ float cnc[CODE_CHUNK];
    __shared__ int   lhist[N_EMBED];            // 4 KB histogram
    __shared__ float red_d[2 * TOK_TILE];
    __shared__ int   red_i[2 * TOK_TILE];
    __shared__ int   bi_l[TOK_TILE];

    const int t = threadIdx.x;
    const int w = t >> 6, lane = t & 63;
    const int wr = w >> 1, wc = w & 1;
    const int r = lane >> 3, c = lane & 7;

    for (int i = t; i < N_EMBED; i += 256) lhist[i] = 0;

    // stage A: 128 x rows -> padded LDS rows (2048 float4 / 256 thr = 8 each)
    {
        const float4* xsrc = (const float4*)(x + (size_t)blockIdx.x * TOK_TILE * DIM);
#pragma unroll
        for (int j = 0; j < 8; ++j) {
            int g = j * 256 + t;
            int tok = g >> 4, kk = (g & 15) << 2;
            float4 v = xsrc[g];
            *(float4*)(xs + tok * APAD + kk) = v;
        }
    }

    float best[8];
    int   bidx[8];
#pragma unroll
    for (int i = 0; i < 8; ++i) { best[i] = 3.4e38f; bidx[i] = 0; }

    for (int chunk = 0; chunk < NCHUNK; ++chunk) {
        float acc[8][8];
#pragma unroll
        for (int i = 0; i < 8; ++i)
#pragma unroll
            for (int j = 0; j < 8; ++j) acc[i][j] = 0.f;

#pragma unroll
        for (int kh = 0; kh < 2; ++kh) {
            __syncthreads();   // prev compute / cnc consumers done
            {   // stage B k-half: 128 codes x 32 k (1024 float4 / 256 thr = 4)
#pragma unroll
                for (int j = 0; j < 4; ++j) {
                    int g = j * 256 + t;
                    int code = g >> 3, kk = (g & 7) << 2;
                    float4 v = *(const float4*)(embedT +
                        ((size_t)(chunk * CODE_CHUNK + code)) * DIM + kh * 32 + kk);
                    *(float4*)(ecs + code * BPAD + kk) = v;
                }
                if (kh == 0 && t < CODE_CHUNK) cnc[t] = cnorm[chunk * CODE_CHUNK + t];
            }
            __syncthreads();

            const float* xbase = xs + (wr * 64) * APAD + kh * 32;
            const float* bbase = ecs + (wc * 64) * BPAD;
#pragma unroll 1
            for (int ks = 0; ks < 8; ++ks) {
                float4 a4[8];
#pragma unroll
                for (int i = 0; i < 8; ++i)
                    a4[i] = *(const float4*)(xbase + (r + 8 * i) * APAD + ks * 4);
#pragma unroll
                for (int j = 0; j < 8; ++j) {
                    float4 b4 = *(const float4*)(bbase + (c + 8 * j) * BPAD + ks * 4);
#pragma unroll
                    for (int i = 0; i < 8; ++i) {
                        acc[i][j] = fmaf(a4[i].x, b4.x, acc[i][j]);
                        acc[i][j] = fmaf(a4[i].y, b4.y, acc[i][j]);
                        acc[i][j] = fmaf(a4[i].z, b4.z, acc[i][j]);
                        acc[i][j] = fmaf(a4[i].w, b4.w, acc[i][j]);
                    }
                }
            }
        }

        // dists + running argmin (codes ascending: strict < = first-index ties)
#pragma unroll
        for (int j = 0; j < 8; ++j) {
            int lc = wc * 64 + c + 8 * j;
            float cn = cnc[lc];
            int gcode = chunk * CODE_CHUNK + lc;
#pragma unroll
            for (int i = 0; i < 8; ++i) {
                float dist = fmaf(-2.f, acc[i][j], cn);
                if (dist < best[i]) { best[i] = dist; bidx[i] = gcode; }
            }
        }
    }

    // reduce over lane columns (c bits = lane bits 0..2)
#pragma unroll
    for (int i = 0; i < 8; ++i) {
        float d = best[i]; int bi = bidx[i];
#pragma unroll
        for (int m = 1; m < 8; m <<= 1) {
            float d2 = __shfl_xor(d, m, 64);
            int   i2 = __shfl_xor(bi, m, 64);
            if (d2 < d || (d2 == d && i2 < bi)) { d = d2; bi = i2; }
        }
        if (c == 0) {
            int tok = wr * 64 + r + 8 * i;
            red_d[wc * TOK_TILE + tok] = d;
            red_i[wc * TOK_TILE + tok] = bi;
        }
    }
    __syncthreads();

    if (t < TOK_TILE) {
        float d0 = red_d[t];            int i0 = red_i[t];
        float d1 = red_d[TOK_TILE + t]; int i1 = red_i[TOK_TILE + t];
        int bi = (d1 < d0 || (d1 == d0 && i1 < i0)) ? i1 : i0;
        bi_l[t] = bi;
        out[OFF_IND + (size_t)blockIdx.x * TOK_TILE + t] = (float)bi;
        atomicAdd(&lhist[bi], 1);
    }
    __syncthreads();

    // quantize write (coalesced) + diff partials
    float ds = 0.f;
    {
        const float4* et4 = (const float4*)embedT;
        float4* qst = (float4*)(out + OFF_QST + (size_t)blockIdx.x * TOK_TILE * DIM);
#pragma unroll
        for (int j = 0; j < 8; ++j) {
            int g = j * 256 + t;
            int tok = g >> 4, f = g & 15;
            int bi = bi_l[tok];
            float4 q = et4[bi * 16 + f];
            float4 xv = *(const float4*)(xs + tok * APAD + (f << 2));
            qst[g] = q;                                // x + stopgrad(q-x) == q
            float ex = q.x - xv.x, ey = q.y - xv.y, ez = q.z - xv.z, ew = q.w - xv.w;
            ds = fmaf(ex, ex, ds); ds = fmaf(ey, ey, ds);
            ds = fmaf(ez, ez, ds); ds = fmaf(ew, ew, ds);
        }
    }
#pragma unroll
    for (int o = 32; o > 0; o >>= 1) ds += __shfl_down(ds, o, 64);
    if (lane == 0) atomicAdd(diff_sum, ds);

    // flush histogram
    for (int i = t; i < N_EMBED; i += 256) {
        int cv = lhist[i];
        if (cv) atomicAdd(&cnt_i[i], cv);
    }
}

// single block, 1024 threads: exclusive prefix over cnt_i -> cursor_i
__global__ __launch_bounds__(1024) void vq_start(
    const int* __restrict__ cnt_i, int* __restrict__ cursor_i)
{
    __shared__ int sc[N_EMBED];
    int e = threadIdx.x;
    int c = cnt_i[e];
    sc[e] = c;
    __syncthreads();
#pragma unroll
    for (int off = 1; off < N_EMBED; off <<= 1) {
        int v = (e >= off) ? sc[e - off] : 0;
        __syncthreads();
        sc[e] += v;
        __syncthreads();
    }
    cursor_i[e] = sc[e] - c;
}

// 512 blocks x 256: bin token ids (and their code) into sorted[]/scode[].
__global__ __launch_bounds__(256) void vq_sort(
    const float* __restrict__ out, int* __restrict__ cursor_i,
    int* __restrict__ sorted, int* __restrict__ scode)
{
    __shared__ int lh[N_EMBED];
    __shared__ int lbase[N_EMBED];
    int t = threadIdx.x;
    for (int i = t; i < N_EMBED; i += 256) lh[i] = 0;
    __syncthreads();
    int tok = blockIdx.x * 256 + t;
    int e = (int)out[OFF_IND + tok];                  // exact small ints in float
    int p = atomicAdd(&lh[e], 1);                     // within-block rank (LDS)
    __syncthreads();
    for (int i = t; i < N_EMBED; i += 256) {
        int c = lh[i];
        if (c) lbase[i] = atomicAdd(&cursor_i[i], c); // reserve [base, base+c)
    }
    __syncthreads();
    int pos = lbase[e] + p;
    sorted[pos] = tok;
    scode[pos] = e;
}

// Token-balanced segment sum: 1024 blocks x 128 tokens. Wave lane = dim.
__global__ __launch_bounds__(256) void vq_sum(
    const float* __restrict__ x, const int* __restrict__ sorted,
    const int* __restrict__ scode, float* __restrict__ es)
{
    __shared__ int ltok[SUM_TPB];
    __shared__ int lcode[SUM_TPB];
    const int t = threadIdx.x;
    const int base = blockIdx.x * SUM_TPB;
    if (t < SUM_TPB) {
        ltok[t]  = sorted[base + t];
        lcode[t] = scode[base + t];
    }
    __syncthreads();

    const int w = t >> 6, d = t & 63;
    const int i0 = w * (SUM_TPB / 4);                 // 32 tokens per wave
    int   cur = lcode[i0];
    float acc = 0.f;
#pragma unroll 4
    for (int i = i0; i < i0 + SUM_TPB / 4; ++i) {
        int e = lcode[i];                             // wave-uniform
        if (e != cur) {                               // uniform branch
            atomicAdd(&es[(size_t)cur * DIM + d], acc);
            acc = 0.f;
            cur = e;
        }
        acc += x[(size_t)ltok[i] * DIM + d];          // 256B coalesced row read
    }
    atomicAdd(&es[(size_t)cur * DIM + d], acc);
}

__global__ __launch_bounds__(1024) void vq_final1(
    const float* __restrict__ cluster_size, const int* __restrict__ cnt_i,
    const float* __restrict__ diff_sum, float* __restrict__ out,
    float* __restrict__ n_val)
{
    int e = threadIdx.x;                            // single block of 1024
    float ncs = cluster_size[e] * DECAYF + OMDF * (float)cnt_i[e];
    out[OFF_NCS + e] = ncs;
    __shared__ float red[16];
    float s = ncs;
#pragma unroll
    for (int o = 32; o > 0; o >>= 1) s += __shfl_down(s, o, 64);
    if ((e & 63) == 0) red[e >> 6] = s;
    __syncthreads();
    if (e == 0) {
        float nsum = 0.f;
#pragma unroll
        for (int i = 0; i < 16; ++i) nsum += red[i];
        *n_val = nsum;
        out[OFF_DIFF] = *diff_sum / (float)((size_t)N_TOKENS * DIM);
    }
}

__global__ __launch_bounds__(256) void vq_final2(
    const float* __restrict__ embed_avg, const float* __restrict__ es,
    const float* __restrict__ n_val, float* __restrict__ out)
{
    int i = blockIdx.x * 256 + threadIdx.x;         // 65536, [d][e] flat
    int e = i & 1023, d = i >> 10;
    float nea = embed_avg[i] * DECAYF + OMDF * es[(size_t)e * DIM + d];
    out[OFF_NEA + i] = nea;
    float ncs = out[OFF_NCS + e];
    float nsum = *n_val;
    float cs = (ncs + EPSF) / (nsum + (float)N_EMBED * EPSF) * nsum;
    out[OFF_NE + i] = nea / cs;
}

extern "C" void kernel_launch(void* const* d_in, const int* in_sizes, int n_in,
                              void* d_out, int out_size, void* d_ws, size_t ws_size,
                              hipStream_t stream)
{
    const float* x            = (const float*)d_in[0];
    const float* embed        = (const float*)d_in[1];
    const float* cluster_size = (const float*)d_in[2];
    const float* embed_avg    = (const float*)d_in[3];
    float* out = (float*)d_out;
    float* ws  = (float*)d_ws;

    float* diff_sum = ws + WS_DIFF;
    float* n_val    = ws + WS_NVAL;
    float* es       = ws + WS_ES;
    float* embedT   = ws + WS_ET;
    float* cnorm    = ws + WS_CNORM;
    int*   iws      = (int*)(ws + WS_IWS);
    int*   cnt_i    = iws;
    int*   cursor_i = iws + 2 * N_EMBED;
    int*   sorted   = iws + 3 * N_EMBED;
    int*   scode    = sorted + N_TOKENS;

    hipMemsetAsync(diff_sum, 0, 2 * sizeof(float), stream);
    hipMemsetAsync(es, 0, N_EMBED * DIM * sizeof(float), stream);   // atomic accumulator
    hipMemsetAsync(cnt_i, 0, N_EMBED * sizeof(int), stream);

    vq_prep_transpose<<<256, 256, 0, stream>>>(embed, embedT);
    vq_prep_norm<<<4, 256, 0, stream>>>(embedT, cnorm);
    vq_main<<<N_TOKENS / TOK_TILE, 256, 0, stream>>>(x, embedT, cnorm, out, diff_sum, cnt_i);
    vq_start<<<1, 1024, 0, stream>>>(cnt_i, cursor_i);
    vq_sort<<<N_TOKENS / 256, 256, 0, stream>>>(out, cursor_i, sorted, scode);
    vq_sum<<<N_TOKENS / SUM_TPB, 256, 0, stream>>>(x, sorted, scode, es);
    vq_final1<<<1, 1024, 0, stream>>>(cluster_size, cnt_i, diff_sum, out, n_val);
    vq_final2<<<256, 256, 0, stream>>>(embed_avg, es, n_val, out);
}